// Round 6
// baseline (121.882 us; speedup 1.0000x reference)
//
#include <hip/hip_runtime.h>
#include <hip/hip_bf16.h>

// Problem constants: B=128, C=21, L=2048, W=32, S=8, O=16, NW=252, NK=4032, K=672
#define Cc   21
#define Ll   2048
#define Oo   16
#define NWw  252
#define NKk  4032
#define Kk   672
#define KP   680   // LDS pitch (bf16) per o-row: conflict-light b128

typedef __attribute__((ext_vector_type(8))) short  short8;  // 8 bf16 = 4 VGPRs
typedef __attribute__((ext_vector_type(4))) float  f32x4;

static __device__ __forceinline__ unsigned short f2bf(float f) {
    union { __hip_bfloat16 h; unsigned short u; } cv;
    cv.h = __float2bfloat16(f);
    return cv.u;
}

static __device__ __forceinline__ short8 cvt8(const float4 a0, const float4 a1) {
    short8 a;
    a[0] = (short)f2bf(a0.x); a[1] = (short)f2bf(a0.y);
    a[2] = (short)f2bf(a0.z); a[3] = (short)f2bf(a0.w);
    a[4] = (short)f2bf(a1.x); a[5] = (short)f2bf(a1.y);
    a[6] = (short)f2bf(a1.z); a[7] = (short)f2bf(a1.w);
    return a;
}

// R17: DIAGNOSTIC x3. R16 (half-breadth serial) stayed under the 44 us
// fill cutoff -> fb_fwd never surfaced. This round runs the EXACT best
// structure (R14, full 256-block grid) three times inside the kernel
// (memory-clobber per iter blocks hoisting; stores idempotent) so the
// dispatch lasts ~70 us and finally yields real counters at full
// contention breadth. Revert to 1 iteration next round.
// Side data from R16: 2x serial work = +7.7 us only (per-pass 15.7 at
// half breadth vs 23.7 at full) -> contention/queueing floor suspected.
// Precommitted read: FETCH/3 vs ~35 MB -> over-fetch?; VALUBusy raw
// >=30% -> issue-bound; Occupancy ~25% + low VALU -> VGPR-capped
// latency floor (next: register diet for 4 waves/SIMD); LDS conflicts.
__global__ __launch_bounds__(512)
void fb_fwd(const float* __restrict__ x, const float* __restrict__ w,
            float* __restrict__ out) {
    __shared__ unsigned short ws[4 * Oo * KP];   // 87.0 KB

    const int bid = blockIdx.x;
    const int r   = bid & 7;            // XCD (round-robin assumption)
    const int idx = bid >> 3;           // 0..31 within XCD
    const int g   = r * 8 + (idx >> 2); // window group (4 windows each)
    if (g > 62) return;                 // 4 idle blocks on XCD 7
    const int bq   = idx & 3;           // batch quarter (32 rows)
    const int tid  = threadIdx.x;
    const int lane = tid & 63;
    const int wv   = tid >> 6;          // 0..7
    const int wm   = wv >> 2;           // m-tile within block (0..1)
    const int ww   = wv & 3;            // window within group
    const int col  = lane & 15;         // MFMA m-row (A) / n-col (B = o)
    const int quad = lane >> 4;         // k-chunk selector
    const int j    = g * 4 + ww;        // global window id
    const int s_loc = (j < NWw - 1) ? ww * 8 : 32;  // j=251: start 2016

#pragma unroll 1
    for (int it = 0; it < 3; ++it) {
        // Opaque wall: forces re-load of x/w each iteration (no hoisting),
        // keeps each iteration a full replica of the real workload.
        asm volatile("" ::: "memory");

        // ---- phase 1: issue w-stage batch A (11 float4/thread) ----
        const f32x4* wj4 = (const f32x4*)w + (size_t)g * 10752;  // 4 windows
        f32x4 wb[11];
#pragma unroll
        for (int p = 0; p < 11; ++p) wb[p] = wj4[tid + p * 512];

        // ---- phase 2: issue the whole A-slice (42 float4 in flight) ----
        const int b = bq * 32 + wm * 16 + col;
        const float* xrow = x + ((size_t)b * Cc) * Ll + g * 32 + s_loc + quad * 8;
        float4 a0[Cc], a1[Cc];
#pragma unroll
        for (int c = 0; c < Cc; ++c) {
            a0[c] = *(const float4*)(xrow + (size_t)c * Ll);
            a1[c] = *(const float4*)(xrow + (size_t)c * Ll + 4);
        }

        // ---- phase 3: cvt + LDS-write w batch A ----
#pragma unroll
        for (int p = 0; p < 11; ++p) {
            int t  = tid + p * 512;
            int oa = t / 168;               // (window,o) pair: 0..63
            int r4 = t - oa * 168;
            *(ushort4*)&ws[oa * KP + r4 * 4] =
                make_ushort4(f2bf(wb[p][0]), f2bf(wb[p][1]),
                             f2bf(wb[p][2]), f2bf(wb[p][3]));
        }

        // ---- phase 4: issue w batch B (10 float4, reuse wb) ----
#pragma unroll
        for (int p = 0; p < 10; ++p) wb[p] = wj4[tid + (11 + p) * 512];

        // ---- phase 5: cvt A to bf16 frags ----
        short8 afr[Cc];
#pragma unroll
        for (int c = 0; c < Cc; ++c) afr[c] = cvt8(a0[c], a1[c]);

        // ---- phase 6: cvt + LDS-write w batch B ----
#pragma unroll
        for (int p = 0; p < 10; ++p) {
            int t  = tid + (11 + p) * 512;
            int oa = t / 168;
            int r4 = t - oa * 168;
            *(ushort4*)&ws[oa * KP + r4 * 4] =
                make_ushort4(f2bf(wb[p][0]), f2bf(wb[p][1]),
                             f2bf(wb[p][2]), f2bf(wb[p][3]));
        }

        __syncthreads();

        // ---- 21-MFMA sweep: B-tile = this wave's window (ww) ----
        const unsigned short* wrow = &ws[(ww * Oo + col) * KP + quad * 8];
        f32x4 acc = {0.f, 0.f, 0.f, 0.f};
#pragma unroll
        for (int c = 0; c < Cc; ++c)
            acc = __builtin_amdgcn_mfma_f32_16x16x32_bf16(
                afr[c], *(const short8*)(wrow + c * 32), acc, 0, 0, 0);

        // ---- C/D layout: col = lane&15, row = quad*4 + reg ----
        const int rbase = bq * 32 + wm * 16 + quad * 4;
        float* op = out + (size_t)rbase * NKk + j * 16 + col;
#pragma unroll
        for (int rr = 0; rr < 4; ++rr)
            __builtin_nontemporal_store(acc[rr], &op[(size_t)rr * NKk]);

        __syncthreads();   // ws re-staged next iteration
    }
}

extern "C" void kernel_launch(void* const* d_in, const int* in_sizes, int n_in,
                              void* d_out, int out_size, void* d_ws, size_t ws_size,
                              hipStream_t stream) {
    const float* x = (const float*)d_in[0];   // (128, 21, 2048) fp32
    const float* w = (const float*)d_in[1];   // (4032, 672) fp32
    float* out = (float*)d_out;               // (128, 4032) fp32
    fb_fwd<<<dim3(256), dim3(512), 0, stream>>>(x, w, out);
}

// Round 7
// 81.568 us; speedup vs baseline: 1.4942x; 1.4942x over previous
//
#include <hip/hip_runtime.h>
#include <hip/hip_bf16.h>

// Problem constants: B=128, C=21, L=2048, W=32, S=8, O=16, NW=252, NK=4032, K=672
#define Cc   21
#define Ll   2048
#define Ss   8
#define Oo   16
#define NWw  252
#define NKk  4032
#define Kk   672
#define KP   680   // LDS pitch (bf16) per o-row: conflict-light b128

typedef __attribute__((ext_vector_type(8))) short  short8;  // 8 bf16 = 4 VGPRs
typedef __attribute__((ext_vector_type(4))) float  f32x4;

static __device__ __forceinline__ unsigned short f2bf(float f) {
    union { __hip_bfloat16 h; unsigned short u; } cv;
    cv.h = __float2bfloat16(f);
    return cv.u;
}

static __device__ __forceinline__ short8 cvt8(const float4 a0, const float4 a1) {
    short8 a;
    a[0] = (short)f2bf(a0.x); a[1] = (short)f2bf(a0.y);
    a[2] = (short)f2bf(a0.z); a[3] = (short)f2bf(a0.w);
    a[4] = (short)f2bf(a1.x); a[5] = (short)f2bf(a1.y);
    a[6] = (short)f2bf(a1.z); a[7] = (short)f2bf(a1.w);
    return a;
}

// R18: K-split wave-pair occupancy attack.
// R17's real counters (first of the session): FETCH 25 MB/iter (<= compulsory
// -> NO over-fetch, BW theories dead), VALUBusy 6%, MfmaUtil 1.2%, LDS
// conflicts negligible, Occupancy 19.8% (8 waves/CU), VGPR 128. The machine
// idles on memory latency with only 8 waves/CU -- and wave count is pinned
// by the decomposition: (128/16 m-tiles) x 252 windows = 2016 waves.
// Fix: split K=672 across wave PAIRS (kh=0: c0-9, kh=1: c10-20), partial
// MFMA accs merged via an 8 KB LDS reduce. 4032 waves = 16/CU = 50%
// occupancy; per-lane burst 42 -> <=22 float4 so the full batch-issue fits
// under the 128-VGPR cap (__launch_bounds__(1024,4) enforces; R17 proved
// 128 VGPR performs). x/w HBM bytes unchanged (c-split disjoint).
// Block: 1 window x 128 batches x 2 k-halves = 1024 thr, grid 256,
// XCD map j=(bid&7)*32+(bid>>3) (unchanged), R13 issue order (w loads
// first), verified MFMA/C layout, NT stores.
__global__ __launch_bounds__(1024, 4)
void fb_fwd(const float* __restrict__ x, const float* __restrict__ w,
            float* __restrict__ out) {
    __shared__ unsigned short ws[Oo * KP];   // 21.76 KB
    __shared__ float rs[8][64][4];           // 8 KB partial-acc scratch

    const int bid = blockIdx.x;
    const int j   = (bid & 7) * 32 + (bid >> 3);          // XCD-grouped window
    if (j >= NWw) return;                                  // 4 idle blocks
    const int s    = (j < NWw - 1) ? j * Ss : (Ll - 32);  // j=251 -> 2016
    const int tid  = threadIdx.x;
    const int lane = tid & 63;
    const int wv   = tid >> 6;       // 0..15
    const int mt   = wv >> 1;        // m-tile (16 batch rows), 0..7
    const int kh   = wv & 1;         // k-half: 0 -> c0..9, 1 -> c10..20
    const int col  = lane & 15;      // MFMA m-row (A) / n-col (B = o)
    const int quad = lane >> 4;      // k-chunk selector

    // ---- phase 1: w loads first (they feed the barrier) ----
    const f32x4* wj4 = (const f32x4*)(w + (size_t)j * Oo * Kk);
    const bool has3 = tid < (Oo * (Kk / 4) - 2 * 1024);    // tid < 640
    f32x4 wb0 = wj4[tid];
    f32x4 wb1 = wj4[tid + 1024];
    f32x4 wb2;
    if (has3) wb2 = wj4[tid + 2048];

    // ---- phase 2: batch-issue this wave's A-half (20/22 float4) ----
    const int row   = mt * 16 + col;        // batch row 0..127
    const int cbase = kh * 10;              // channel base
    const float* xrow = x + ((size_t)row * Cc + cbase) * Ll + s + quad * 8;
    float4 a0[11], a1[11];
#pragma unroll
    for (int c = 0; c < 10; ++c) {
        a0[c] = *(const float4*)(xrow + (size_t)c * Ll);
        a1[c] = *(const float4*)(xrow + (size_t)c * Ll + 4);
    }
    if (kh) {   // wave-uniform branch: kh=1 owns 11 channels
        a0[10] = *(const float4*)(xrow + (size_t)10 * Ll);
        a1[10] = *(const float4*)(xrow + (size_t)10 * Ll + 4);
    }

    // ---- phase 3: cvt + LDS-write w (waits only the 3 w loads) ----
    {
        int t = tid;         int oa = t / 168; int r4 = t - oa * 168;
        *(ushort4*)&ws[oa * KP + r4 * 4] =
            make_ushort4(f2bf(wb0[0]), f2bf(wb0[1]), f2bf(wb0[2]), f2bf(wb0[3]));
        t = tid + 1024;      oa = t / 168;     r4 = t - oa * 168;
        *(ushort4*)&ws[oa * KP + r4 * 4] =
            make_ushort4(f2bf(wb1[0]), f2bf(wb1[1]), f2bf(wb1[2]), f2bf(wb1[3]));
        if (has3) {
            t = tid + 2048;  oa = t / 168;     r4 = t - oa * 168;
            *(ushort4*)&ws[oa * KP + r4 * 4] =
                make_ushort4(f2bf(wb2[0]), f2bf(wb2[1]), f2bf(wb2[2]), f2bf(wb2[3]));
        }
    }
    __syncthreads();

    // ---- MFMA sweep over this wave's channels (cvt just-in-time) ----
    const unsigned short* wrow = &ws[col * KP + quad * 8 + cbase * 32];
    f32x4 acc = {0.f, 0.f, 0.f, 0.f};
#pragma unroll
    for (int c = 0; c < 10; ++c) {
        short8 afr = cvt8(a0[c], a1[c]);
        acc = __builtin_amdgcn_mfma_f32_16x16x32_bf16(
            afr, *(const short8*)(wrow + c * 32), acc, 0, 0, 0);
    }
    if (kh) {
        short8 afr = cvt8(a0[10], a1[10]);
        acc = __builtin_amdgcn_mfma_f32_16x16x32_bf16(
            afr, *(const short8*)(wrow + 10 * 32), acc, 0, 0, 0);
    }

    // ---- cross-wave K-reduce: kh=1 -> LDS, kh=0 adds + stores ----
    if (kh) *(f32x4*)rs[mt][lane] = acc;
    __syncthreads();
    if (!kh) {
        const f32x4 other = *(const f32x4*)rs[mt][lane];
        const int rbase = mt * 16 + quad * 4;
        float* op = out + (size_t)rbase * NKk + j * 16 + col;
#pragma unroll
        for (int rr = 0; rr < 4; ++rr)
            __builtin_nontemporal_store(acc[rr] + other[rr], &op[(size_t)rr * NKk]);
    }
}

extern "C" void kernel_launch(void* const* d_in, const int* in_sizes, int n_in,
                              void* d_out, int out_size, void* d_ws, size_t ws_size,
                              hipStream_t stream) {
    const float* x = (const float*)d_in[0];   // (128, 21, 2048) fp32
    const float* w = (const float*)d_in[1];   // (4032, 672) fp32
    float* out = (float*)d_out;               // (128, 4032) fp32
    fb_fwd<<<dim3(256), dim3(1024), 0, stream>>>(x, w, out);
}